// Round 8
// baseline (6118.615 us; speedup 1.0000x reference)
//
#include <hip/hip_runtime.h>
#include <math.h>

#define NT 512        // time steps
#define NB 512        // batch
#define HID 128
#define NIN 10
#define NC 10         // memory cells
#define CW 20         // cell width
#define NIF 88        // interface size
#define NOUT 10
#define GB 2          // batches per workgroup
#define BLK 512       // 8 waves; alloc law grants 128 VGPR at this size

typedef _Float16 h1;
typedef _Float16 h2 __attribute__((ext_vector_type(2)));

// ---- fast transcendentals (abs err ~1e-7, vs fp16 noise 5e-4) ----
__device__ __forceinline__ float rcpf(float x) { return __builtin_amdgcn_rcpf(x); }
__device__ __forceinline__ float sigf(float x) { return rcpf(1.0f + __expf(-x)); }
__device__ __forceinline__ float tanhf_(float x) {
  float xc = fminf(fmaxf(x, -15.f), 15.f);
  float e = __expf(2.f * xc);
  return (e - 1.f) * rcpf(e + 1.f);
}
// jax.nn.softplus == logaddexp(x, 0)
__device__ __forceinline__ float splus(float x) { return fmaxf(x, 0.0f) + __logf(1.f + __expf(-fabsf(x))); }

// fp16 pair dot with fp32 accumulate: v_dot2_f32_f16
__device__ __forceinline__ float dot2(h2 a, h2 b, float c) {
#if __has_builtin(__builtin_amdgcn_fdot2)
  return __builtin_amdgcn_fdot2(a, b, c, false);
#else
  c += (float)a.x * (float)b.x;
  c += (float)a.y * (float)b.y;
  return c;
#endif
}

// within-wave LDS ordering fence (no workgroup barrier)
#define LDSFENCE() do { asm volatile("s_waitcnt lgkmcnt(0)" ::: "memory"); \
                        __builtin_amdgcn_sched_barrier(0); } while (0)

#define BC(f) __builtin_bit_cast(h2, f)

// one float4 of packed fp16 weights (8 elems) x 8 fp16 activations, 2 batches
#define DOTF4(W, fa, fb)                                   \
  a0 = dot2(BC((W).x), BC((fa).x), a0);                    \
  a1 = dot2(BC((W).x), BC((fb).x), a1);                    \
  a2 = dot2(BC((W).y), BC((fa).y), a2);                    \
  a3 = dot2(BC((W).y), BC((fb).y), a3);                    \
  a0 = dot2(BC((W).z), BC((fa).z), a0);                    \
  a1 = dot2(BC((W).z), BC((fb).z), a1);                    \
  a2 = dot2(BC((W).w), BC((fa).w), a2);                    \
  a3 = dot2(BC((W).w), BC((fb).w), a3);

#define LSTEP(W, i, Pa, Pb) { float4 fa = (Pa)[i], fb = (Pb)[i]; DOTF4(W, fa, fb) }

__device__ __forceinline__ float4 pack8(const float* p) {
  h2 v0, v1, v2, v3;
  v0.x=(h1)p[0]; v0.y=(h1)p[1]; v1.x=(h1)p[2]; v1.y=(h1)p[3];
  v2.x=(h1)p[4]; v2.y=(h1)p[5]; v3.x=(h1)p[6]; v3.y=(h1)p[7];
  float4 r;
  r.x=__builtin_bit_cast(float,v0); r.y=__builtin_bit_cast(float,v1);
  r.z=__builtin_bit_cast(float,v2); r.w=__builtin_bit_cast(float,v3);
  return r;
}

// ---- pack streamed weights (fp16, transposed [chunk][row]) into d_ws ----
// ws[c*512 + r] = Whh1[r][8c..8c+7] (c<16); ws[(16+c2)*512+r] = Wih1[r][(14+c2)*8 ..]
__global__ __launch_bounds__(256) void dnc_pack_kernel(
    const float* __restrict__ Wih1, const float* __restrict__ Whh1, float4* __restrict__ ws)
{
  int i = blockIdx.x * 256 + threadIdx.x;   // 0..9215
  if (i < 16*512) {
    int c = i >> 9, rr = i & 511;
    ws[i] = pack8(Whh1 + (size_t)rr*HID + 8*c);
  } else if (i < 18*512) {
    int j = i - 16*512; int c2 = j >> 9, rr = j & 511;
    ws[i] = pack8(Wih1 + (size_t)rr*HID + (14 + c2)*8);
  }
}

__global__ __launch_bounds__(BLK)
void dnc_olap_kernel(
    const float* __restrict__ x,
    const float* __restrict__ Wih0, const float* __restrict__ Whh0, const float* __restrict__ b0,
    const float* __restrict__ Wih1, const float* __restrict__ Whh1, const float* __restrict__ b1,
    const float* __restrict__ Wif,  const float* __restrict__ bif,
    const float* __restrict__ Wout, const float* __restrict__ bout,
    const float4* __restrict__ wsT,
    float* __restrict__ out)
{
  // ---- LDS (~148 KB -> 1 block/CU) ----
  __shared__ __align__(16) float4 s_wih1T[14][512];   // [chunk][row]: Wih1 k=8c..8c+7, lane-contiguous
  __shared__ __align__(16) float4 s_wifT[16*89];      // [chunk*89+row]: Wif, stride-89 padded
  __shared__ __align__(16) float s_g[GB][512];        // gate pre-activations
  __shared__ __align__(16) float s_fp[NIF][9];        // interface partials [row][2c+b]
  __shared__ float s_bif[NIF];
  __shared__ __align__(16) h1   s_xbuf[2][GB][16];    // double-buffered x_t (10 + pad6) fp16
  __shared__ __align__(16) h1   s_rvh[GB][24];        // rv (20 + pad4) fp16
  __shared__ __align__(16) h1   s_h0h[GB][HID];
  __shared__ __align__(16) h1   s_h1h[GB][HID];
  __shared__ __align__(16) h1   s_ctrlh[GB][HID];
  __shared__ __align__(16) float s_ctrl[GB][HID];     // fp32 for epilogue
  __shared__ __align__(16) float s_mem[GB][NC][CW];
  __shared__ float s_rk[GB][CW], s_wk[GB][CW], s_er[GB][CW], s_wv[GB][CW];
  __shared__ float s_mraw[GB][3];
  __shared__ float s_sc[GB][8];     // 0:rs 1:ws 2:fg 3:ga 4:gw 5:m0 6:m1 7:m2
  __shared__ float s_usage[GB][NC], s_u[GB][NC];
  __shared__ float s_prec[GB][NC], s_prec2[GB][NC];
  __shared__ float s_link[GB][NC][NC];
  __shared__ float s_rw[GB][NC], s_ww[GB][NC];
  __shared__ float s_rv[GB][CW];
  __shared__ float s_cw[GB][NC], s_cr[GB][NC], s_fwd[GB][NC], s_bwd[GB][NC];

  const int tid = threadIdx.x;
  const int bg  = blockIdx.x * GB;
  const int r   = tid;              // gate row owned by this thread

  // ---- register weights: Wih0 padded row (5 f4) + Whh0 full row (16 f4) = 84 VGPRs ----
  // padded inp layout: [x(10), pad(6), rv(20), pad(2)] -> A0,A1 = x part; A2..A4 = rv part
  float4 A0,A1,A2,A3,A4;
  float4 B0,B1,B2,B3,B4,B5,B6,B7,B8,B9,B10,B11,B12,B13,B14,B15;
  float b0r, b1r;
  {
    const float* p = Wih0 + (size_t)r * (NIN + CW);
    A0 = pack8(p);
    { h2 v0,z; v0.x=(h1)p[8]; v0.y=(h1)p[9]; z.x=(h1)0.f; z.y=(h1)0.f;
      float4 f; f.x=__builtin_bit_cast(float,v0); f.y=__builtin_bit_cast(float,z);
      f.z=f.y; f.w=f.y; A1=f; }
    A2 = pack8(p+10); A3 = pack8(p+18);
    { h2 v0,v1,z; v0.x=(h1)p[26]; v0.y=(h1)p[27]; v1.x=(h1)p[28]; v1.y=(h1)p[29];
      z.x=(h1)0.f; z.y=(h1)0.f;
      float4 f; f.x=__builtin_bit_cast(float,v0); f.y=__builtin_bit_cast(float,v1);
      f.z=__builtin_bit_cast(float,z); f.w=f.z; A4=f; }
    const float* q0 = Whh0 + (size_t)r*HID;
    B0 =pack8(q0);    B1 =pack8(q0+8);  B2 =pack8(q0+16);  B3 =pack8(q0+24);
    B4 =pack8(q0+32); B5 =pack8(q0+40); B6 =pack8(q0+48);  B7 =pack8(q0+56);
    B8 =pack8(q0+64); B9 =pack8(q0+72); B10=pack8(q0+80);  B11=pack8(q0+88);
    B12=pack8(q0+96); B13=pack8(q0+104);B14=pack8(q0+112); B15=pack8(q0+120);
    b0r = b0[r]; b1r = b1[r];
  }

  // ---- LDS weight staging (one-time, transposed, lane-contiguous) ----
  for (int idx = tid; idx < 14*512; idx += BLK) {
    int c = idx >> 9, rr = idx & 511;
    s_wih1T[c][rr] = pack8(Wih1 + (size_t)rr*HID + 8*c);
  }
  for (int idx = tid; idx < 16*NIF; idx += BLK) {
    int j = idx / NIF, q = idx - j*NIF;
    s_wifT[j*89 + q] = pack8(Wif + (size_t)q*HID + 8*j);
  }
  if (tid < NIF) s_bif[tid] = bif[tid];

  // ---- zero-init state ----
  if (tid < GB*HID) { int b=tid>>7, j=tid&127;
    s_h0h[b][j]=(h1)0.f; s_h1h[b][j]=(h1)0.f; s_ctrlh[b][j]=(h1)0.f; s_ctrl[b][j]=0.f; }
  for (int i = tid; i < GB*NC*CW; i += BLK) { int b=i/(NC*CW), e=i%(NC*CW);
    s_mem[b][e/CW][e%CW]=0.f; }
  for (int i = tid; i < GB*NC*NC; i += BLK) { int b=i/(NC*NC), e=i%(NC*NC);
    s_link[b][e/NC][e%NC]=0.f; }
  if (tid < GB*NC) { int b=tid/NC, n=tid%NC;
    s_usage[b][n]=0.f; s_prec[b][n]=0.f; s_rw[b][n]=0.f; s_ww[b][n]=0.f; }
  if (tid < GB*CW) { int b=tid/CW, c=tid%CW; s_rv[b][c]=0.f; }
  if (tid < GB*24) { int b=tid/24, c=tid%24; s_rvh[b][c]=(h1)0.f; }
  if (tid < 2*GB*16) { int u=tid, d=u>>5, b=(u>>4)&1, i=u&15;
    float v = 0.f;
    if (d == 0 && i < NIN) v = x[((size_t)(bg+b)*NT + 0)*NIN + i];
    s_xbuf[d][b][i] = (h1)v;
  }
  float c0r = 0.f, c1r = 0.f;   // LSTM cell states (threads 0..255: b=tid>>7, j=tid&127)
  __syncthreads();

  // ---- full DNC tail for step t-1 (wave 7 only), fences not barriers ----
  auto dnc_tail = [&](int lane) {
    // F-combine: xi = bif + sum of 4 partials, fused transforms
    #pragma unroll
    for (int e = lane; e < 2*NIF; e += 64) {
      int b = e & 1, q = e >> 1;
      float a = s_bif[q];
      #pragma unroll
      for (int c = 0; c < 4; ++c) a += s_fp[q][2*c+b];
      if      (q < 20)  s_rk[b][q]    = tanhf_(a);
      else if (q == 20) s_sc[b][0]    = splus(a);
      else if (q < 41)  s_wk[b][q-21] = tanhf_(a);
      else if (q == 41) s_sc[b][1]    = splus(a);
      else if (q < 62)  s_er[b][q-42] = sigf(a);
      else if (q < 82)  s_wv[b][q-62] = tanhf_(a);
      else if (q == 82) s_sc[b][2]    = sigf(a);
      else if (q == 83) s_sc[b][3]    = sigf(a);
      else if (q == 84) s_sc[b][4]    = sigf(a);
      else              s_mraw[b][q-85] = a;
    }
    LDSFENCE();

    // H: usage/psi + write-content sims + modes softmax
    if (lane < GB*NC) {
      int b = lane/NC, n = lane%NC;
      float fg = s_sc[b][2];
      float psi = 1.f - fg * s_rw[b][n];
      float u = s_usage[b][n], w = s_ww[b][n];
      u = (u + w - u*w) * psi;
      s_usage[b][n] = u;
      s_u[b][n] = 1e-6f + (1.0f - 1e-6f) * u;
      float dot=0.f, mn=0.f, kn=0.f;
      #pragma unroll
      for (int c = 0; c < CW; ++c) {
        float m = s_mem[b][n][c], k = s_wk[b][c];
        dot += k*m; mn += m*m; kn += k*k;
      }
      s_cw[b][n] = dot * rcpf(sqrtf(kn)*sqrtf(mn) + 1e-6f) * s_sc[b][1];
    } else if (lane < GB*NC + GB) {
      int b = lane - GB*NC;
      float m0=s_mraw[b][0], m1=s_mraw[b][1], m2=s_mraw[b][2];
      float mm = fmaxf(m0, fmaxf(m1, m2));
      float e0=__expf(m0-mm), e1=__expf(m1-mm), e2=__expf(m2-mm);
      float es = rcpf(e0+e1+e2);
      s_sc[b][5]=e0*es; s_sc[b][6]=e1*es; s_sc[b][7]=e2*es;
    }
    LDSFENCE();

    // I: cw softmax + rank-based allocation + new ww
    if (lane < GB*NC) {
      int b = lane/NC, n = lane%NC;
      float mx = -1e30f;
      #pragma unroll
      for (int m = 0; m < NC; ++m) mx = fmaxf(mx, s_cw[b][m]);
      float sm = 0.f;
      #pragma unroll
      for (int m = 0; m < NC; ++m) sm += __expf(s_cw[b][m]-mx);
      float cwv = __expf(s_cw[b][n]-mx) * rcpf(sm);
      float un = s_u[b][n];
      float excl = 1.f;
      #pragma unroll
      for (int m = 0; m < NC; ++m) {
        float um = s_u[b][m];
        bool before = (um < un) || (um == un && m < n);
        excl *= before ? um : 1.f;
      }
      float alloc = (1.f - un) * excl;
      float ga = s_sc[b][3], gw = s_sc[b][4];
      s_ww[b][n] = gw * (ga*alloc + (1.f-ga)*cwv);
    }
    LDSFENCE();

    // J: memory write + link update (old prec) + prec2
    #pragma unroll
    for (int e = lane; e < GB*NC*CW; e += 64) {
      int b = e/(NC*CW), rr = (e%(NC*CW))/CW, c = e%CW;
      float w = s_ww[b][rr];
      s_mem[b][rr][c] = s_mem[b][rr][c] * (1.f - w*s_er[b][c]) + w*s_wv[b][c];
    }
    #pragma unroll
    for (int e = lane; e < GB*NC*NC; e += 64) {
      int b = e/(NC*NC), i = (e%(NC*NC))/NC, j = e%NC;
      float wi = s_ww[b][i], wj = s_ww[b][j];
      float l = (1.f - wi - wj)*s_link[b][i][j] + wi*s_prec[b][j];
      s_link[b][i][j] = (i==j) ? 0.f : l;
    }
    if (lane < GB*NC) {
      int b = lane/NC, n = lane%NC;
      float sw2 = 0.f;
      #pragma unroll
      for (int m = 0; m < NC; ++m) sw2 += s_ww[b][m];
      s_prec2[b][n] = (1.f - sw2)*s_prec[b][n] + s_ww[b][n];
    }
    LDSFENCE();

    // K: commit prec, fwd/bwd on new link, read-content sims on new mem
    if (lane < GB*NC) {
      int b = lane/NC, m = lane%NC;
      s_prec[b][m] = s_prec2[b][m];
      float a = 0.f;
      #pragma unroll
      for (int n = 0; n < NC; ++n) a += s_rw[b][n]*s_link[b][m][n];
      s_fwd[b][m] = a;
    } else if (lane < 2*GB*NC) {
      int q = lane - GB*NC, b = q/NC, m = q%NC;
      float a = 0.f;
      #pragma unroll
      for (int n = 0; n < NC; ++n) a += s_rw[b][n]*s_link[b][n][m];
      s_bwd[b][m] = a;
    } else if (lane < 3*GB*NC) {
      int q = lane - 2*GB*NC, b = q/NC, n = q%NC;
      float dot=0.f, mn=0.f, kn=0.f;
      #pragma unroll
      for (int c = 0; c < CW; ++c) {
        float m = s_mem[b][n][c], k = s_rk[b][c];
        dot += k*m; mn += m*m; kn += k*k;
      }
      s_cr[b][n] = dot * rcpf(sqrtf(kn)*sqrtf(mn)+1e-6f) * s_sc[b][0];
    }
    LDSFENCE();

    // L: cr softmax + new read weights
    if (lane < GB*NC) {
      int b = lane/NC, n = lane%NC;
      float mx = -1e30f;
      #pragma unroll
      for (int m = 0; m < NC; ++m) mx = fmaxf(mx, s_cr[b][m]);
      float sm = 0.f;
      #pragma unroll
      for (int m = 0; m < NC; ++m) sm += __expf(s_cr[b][m]-mx);
      float cr = __expf(s_cr[b][n]-mx)*rcpf(sm);
      s_rw[b][n] = s_sc[b][5]*s_bwd[b][n] + s_sc[b][6]*cr + s_sc[b][7]*s_fwd[b][n];
    }
    LDSFENCE();

    // M: read vectors -> s_rv (fp32) + s_rvh (fp16)
    if (lane < GB*CW) {
      int b = lane/CW, c = lane%CW;
      float a = 0.f;
      #pragma unroll
      for (int n = 0; n < NC; ++n) a += s_rw[b][n]*s_mem[b][n][c];
      s_rv[b][c] = a;
      s_rvh[b][c] = (h1)a;
    }
  };

  for (int t = 0; t < NT; ++t) {
    // ================= R1: {wave7: DNC(t-1)} ∥ {all: G0-partial + G1-partial} ===========
    if (tid >= 448) {
      const int lane = tid - 448;
      float xv = 0.f;
      if (lane < GB*NIN && (t+1) < NT) {
        int b = lane/NIN, i = lane%NIN;
        xv = x[((size_t)(bg+b)*NT + (t+1))*NIN + i];
      }
      if (t > 0) dnc_tail(lane);
      if (lane < GB*NIN && (t+1) < NT) {
        int b = lane/NIN, i = lane%NIN;
        s_xbuf[(t+1)&1][b][i] = (h1)xv;
      }
    }
    // all threads (wave 7 after its DNC): G0p = b0 + A_x·x_t + Whh0·h0_{t-1}
    unsigned lnd = 0;
    asm volatile("" : "+v"(lnd));   // launder: defeat LICM hoisting of invariant loads
    const float4* WS = (const float4*)((const char*)wsT + lnd);
    float4 u0 = WS[0*512+tid], u1 = WS[1*512+tid];
    float4 t0 = WS[2*512+tid], t1 = WS[3*512+tid];
    float r0a, r0b, g1a, g1b;
    {
      float a0=b0r, a1=b0r, a2=0.f, a3=0.f;
      const float4* Xa = (const float4*)&s_xbuf[t&1][0][0];
      const float4* Xb = (const float4*)&s_xbuf[t&1][1][0];
      LSTEP(A0,0,Xa,Xb) LSTEP(A1,1,Xa,Xb)
      const float4* Ha = (const float4*)s_h0h[0];
      const float4* Hb = (const float4*)s_h0h[1];
      LSTEP(B0,0,Ha,Hb)   LSTEP(B1,1,Ha,Hb)   LSTEP(B2,2,Ha,Hb)   LSTEP(B3,3,Ha,Hb)
      LSTEP(B4,4,Ha,Hb)   LSTEP(B5,5,Ha,Hb)   LSTEP(B6,6,Ha,Hb)   LSTEP(B7,7,Ha,Hb)
      LSTEP(B8,8,Ha,Hb)   LSTEP(B9,9,Ha,Hb)   LSTEP(B10,10,Ha,Hb) LSTEP(B11,11,Ha,Hb)
      LSTEP(B12,12,Ha,Hb) LSTEP(B13,13,Ha,Hb) LSTEP(B14,14,Ha,Hb) LSTEP(B15,15,Ha,Hb)
      r0a = a0+a2; r0b = a1+a3;
    }
    // G1p = Whh1·h1_{t-1} (streamed, 16 chunks, pipelined pairs)
    {
      float a0=0.f, a1=0.f, a2=0.f, a3=0.f;
      const float4* Ga = (const float4*)s_h1h[0];
      const float4* Gb = (const float4*)s_h1h[1];
      LSTEP(u0, 0,Ga,Gb) LSTEP(u1, 1,Ga,Gb)
      u0 = WS[ 4*512+tid]; u1 = WS[ 5*512+tid];
      LSTEP(t0, 2,Ga,Gb) LSTEP(t1, 3,Ga,Gb)
      t0 = WS[ 6*512+tid]; t1 = WS[ 7*512+tid];
      LSTEP(u0, 4,Ga,Gb) LSTEP(u1, 5,Ga,Gb)
      u0 = WS[ 8*512+tid]; u1 = WS[ 9*512+tid];
      LSTEP(t0, 6,Ga,Gb) LSTEP(t1, 7,Ga,Gb)
      t0 = WS[10*512+tid]; t1 = WS[11*512+tid];
      LSTEP(u0, 8,Ga,Gb) LSTEP(u1, 9,Ga,Gb)
      u0 = WS[12*512+tid]; u1 = WS[13*512+tid];
      LSTEP(t0,10,Ga,Gb) LSTEP(t1,11,Ga,Gb)
      t0 = WS[14*512+tid]; t1 = WS[15*512+tid];
      LSTEP(u0,12,Ga,Gb) LSTEP(u1,13,Ga,Gb)
      LSTEP(t0,14,Ga,Gb) LSTEP(t1,15,Ga,Gb)
      g1a = a0+a2; g1b = a1+a3;
    }
    __syncthreads();

    // ---- P2: finish gates0 with rv part ----
    {
      float a0=r0a, a1=r0b, a2=0.f, a3=0.f;
      const float4* Ra = (const float4*)&s_rvh[0][0];
      const float4* Rb = (const float4*)&s_rvh[1][0];
      LSTEP(A2,0,Ra,Rb) LSTEP(A3,1,Ra,Rb) LSTEP(A4,2,Ra,Rb)
      s_g[0][r] = a0+a2; s_g[1][r] = a1+a3;
    }
    __syncthreads();

    // ---- P3 (C): LSTM0 nonlinearity ----
    if (tid < GB*HID) {
      int b = tid>>7, j = tid&127;
      float gi=s_g[b][j], gf=s_g[b][HID+j], gg=s_g[b][2*HID+j], go=s_g[b][3*HID+j];
      float c = sigf(gf)*c0r + sigf(gi)*tanhf_(gg);
      c0r = c;
      float h = sigf(go)*tanhf_(c);
      s_h0h[b][j] = (h1)h;
    }
    __syncthreads();

    // ---- P4 (D): gates1 = G1p + b1 + Wih1·h0_new (14 LDS chunks + 2 streamed) ----
    {
      float4 v0 = WS[16*512+tid], v1 = WS[17*512+tid];
      float a0 = g1a + b1r, a1 = g1b + b1r, a2=0.f, a3=0.f;
      const float4* Ha = (const float4*)s_h0h[0];
      const float4* Hb = (const float4*)s_h0h[1];
      { float4 w=s_wih1T[ 0][r]; LSTEP(w, 0,Ha,Hb) }
      { float4 w=s_wih1T[ 1][r]; LSTEP(w, 1,Ha,Hb) }
      { float4 w=s_wih1T[ 2][r]; LSTEP(w, 2,Ha,Hb) }
      { float4 w=s_wih1T[ 3][r]; LSTEP(w, 3,Ha,Hb) }
      { float4 w=s_wih1T[ 4][r]; LSTEP(w, 4,Ha,Hb) }
      { float4 w=s_wih1T[ 5][r]; LSTEP(w, 5,Ha,Hb) }
      { float4 w=s_wih1T[ 6][r]; LSTEP(w, 6,Ha,Hb) }
      { float4 w=s_wih1T[ 7][r]; LSTEP(w, 7,Ha,Hb) }
      { float4 w=s_wih1T[ 8][r]; LSTEP(w, 8,Ha,Hb) }
      { float4 w=s_wih1T[ 9][r]; LSTEP(w, 9,Ha,Hb) }
      { float4 w=s_wih1T[10][r]; LSTEP(w,10,Ha,Hb) }
      { float4 w=s_wih1T[11][r]; LSTEP(w,11,Ha,Hb) }
      { float4 w=s_wih1T[12][r]; LSTEP(w,12,Ha,Hb) }
      { float4 w=s_wih1T[13][r]; LSTEP(w,13,Ha,Hb) }
      LSTEP(v0,14,Ha,Hb) LSTEP(v1,15,Ha,Hb)
      s_g[0][r] = a0+a2; s_g[1][r] = a1+a3;
    }
    __syncthreads();

    // ---- P5 (E): LSTM1 nonlinearity + ctrl clip ----
    if (tid < GB*HID) {
      int b = tid>>7, j = tid&127;
      float gi=s_g[b][j], gf=s_g[b][HID+j], gg=s_g[b][2*HID+j], go=s_g[b][3*HID+j];
      float c = sigf(gf)*c1r + sigf(gi)*tanhf_(gg);
      c1r = c;
      float h = sigf(go)*tanhf_(c);
      float ctl = fminf(fmaxf(h, -20.f), 20.f);
      s_h1h[b][j] = (h1)h;
      s_ctrl[b][j] = ctl;
      s_ctrlh[b][j] = (h1)ctl;
    }
    __syncthreads();

    // ---- P6 (F): interface partials, 4 threads per row ----
    if (tid < 4*NIF) {
      int q = tid >> 2, c = tid & 3;
      float a0=0.f, a1=0.f, a2=0.f, a3=0.f;
      const float4* Ca = (const float4*)s_ctrlh[0];
      const float4* Cb = (const float4*)s_ctrlh[1];
      float4 w0 = s_wifT[(4*c+0)*89 + q];
      float4 w1 = s_wifT[(4*c+1)*89 + q];
      float4 w2 = s_wifT[(4*c+2)*89 + q];
      float4 w3 = s_wifT[(4*c+3)*89 + q];
      LSTEP(w0, 4*c+0, Ca, Cb) LSTEP(w1, 4*c+1, Ca, Cb)
      LSTEP(w2, 4*c+2, Ca, Cb) LSTEP(w3, 4*c+3, Ca, Cb)
      s_fp[q][2*c  ] = a0+a2;
      s_fp[q][2*c+1] = a1+a3;
    }
    __syncthreads();
  }

  // ---- final DNC for t = NT-1 ----
  if (tid >= 448) dnc_tail(tid - 448);
  __syncthreads();

  // ---- epilogue: y_T = [ctrl, rv] @ Wout^T + bout ----
  if (tid < GB*NOUT) {
    int b = tid/NOUT, o = tid%NOUT;
    float a = bout[o];
    const float* Wr = Wout + o*(HID+CW);
    #pragma unroll 4
    for (int k = 0; k < HID; ++k) a += Wr[k]*s_ctrl[b][k];
    #pragma unroll
    for (int c = 0; c < CW; ++c) a += Wr[HID+c]*s_rv[b][c];
    out[(size_t)(bg+b)*NOUT + o] = a;
  }
}

extern "C" void kernel_launch(void* const* d_in, const int* in_sizes, int n_in,
                              void* d_out, int out_size, void* d_ws, size_t ws_size,
                              hipStream_t stream) {
  (void)in_sizes; (void)n_in; (void)out_size; (void)ws_size;
  const float* x    = (const float*)d_in[0];
  const float* Wih0 = (const float*)d_in[1];
  const float* Whh0 = (const float*)d_in[2];
  const float* b0   = (const float*)d_in[3];
  const float* Wih1 = (const float*)d_in[4];
  const float* Whh1 = (const float*)d_in[5];
  const float* b1   = (const float*)d_in[6];
  const float* Wif  = (const float*)d_in[7];
  const float* bif  = (const float*)d_in[8];
  const float* Wout = (const float*)d_in[9];
  const float* bout = (const float*)d_in[10];
  float* out = (float*)d_out;
  float4* ws = (float4*)d_ws;

  dnc_pack_kernel<<<dim3(36), dim3(256), 0, stream>>>(Wih1, Whh1, ws);
  dnc_olap_kernel<<<dim3(NB/GB), dim3(BLK), 0, stream>>>(
      x, Wih0, Whh0, b0, Wih1, Whh1, b1, Wif, bif, Wout, bout, ws, out);
}